// Round 2
// baseline (144.414 us; speedup 1.0000x reference)
//
#include <hip/hip_runtime.h>

// IDCT (DCT-III) of 4096 rows x 4096 cols via per-row 4096-point complex FFT
// (Makhoul single-FFT formulation):
//   a_n = w_n * x_n * exp(+j*pi*n/(2N)),  w_0=1, w_n=2
//   u_m = sum_n a_n exp(+j*2*pi*n*m/N)      (N-point, sign +1, unnormalized)
//   y[2m] = Re u[m],  y[2m+1] = Re u[N-1-m],  m = 0..N/2-1
//
// One workgroup (256 threads) per row. Radix-16, 3 stages (16^3 = 4096),
// Stockham ordering, in-place LDS with read/barrier/write.
//
// R2 changes vs R1 (43.7us, occ 23%, 3.1M bank-conflict cycles):
//  - float2-interleaved LDS, exactly 32 KB -> 5 blocks/CU (was 43KB -> 3)
//  - XOR swizzle (p ^ ((p>>3)&0xE)) replaces +1/16 padding; verified
//    conflict-free for every access pattern (stage-1 b128 writes tile all
//    32 banks; strided b64 reads/writes hit 16 distinct bank-pairs/group)
//  - b128/b64 LDS ops: 88 wave LDS instrs/thread vs 160
//  - twiddle LDS table removed; read expk directly (L1-resident, 32KB)

#define NFFT 4096
#define NT   256
#define SWZ(p) ((p) ^ (((p) >> 3) & 0xE))   // flips float2-index bits 1..3 by bits 4..6

__device__ __forceinline__ void cmul(float ar, float ai, float br, float bi,
                                     float& orr, float& oii) {
    orr = ar * br - ai * bi;
    oii = ar * bi + ai * br;
}

// 16-point DFT, sign +1 (inverse direction), natural order, in place.
__device__ __forceinline__ void dft16(float vr[16], float vi[16]) {
    constexpr float WR[4][4] = {
        {1.f, 1.f, 1.f, 1.f},
        {1.f,  0.92387953251128674f,  0.70710678118654752f,  0.38268343236508977f},
        {1.f,  0.70710678118654752f,  0.f,                  -0.70710678118654752f},
        {1.f,  0.38268343236508977f, -0.70710678118654752f, -0.92387953251128674f}};
    constexpr float WI[4][4] = {
        {0.f, 0.f, 0.f, 0.f},
        {0.f,  0.38268343236508977f,  0.70710678118654752f,  0.92387953251128674f},
        {0.f,  0.70710678118654752f,  1.f,                   0.70710678118654752f},
        {0.f,  0.92387953251128674f,  0.70710678118654752f, -0.38268343236508977f}};
    float ur[16], ui[16];
#pragma unroll
    for (int p = 0; p < 4; ++p) {
        float apcr = vr[p] + vr[p + 8],      apci = vi[p] + vi[p + 8];
        float amcr = vr[p] - vr[p + 8],      amci = vi[p] - vi[p + 8];
        float bpdr = vr[p + 4] + vr[p + 12], bpdi = vi[p + 4] + vi[p + 12];
        float bmdr = vr[p + 4] - vr[p + 12], bmdi = vi[p + 4] - vi[p + 12];
        float y0r = apcr + bpdr, y0i = apci + bpdi;
        float y1r = amcr - bmdi, y1i = amci + bmdr;
        float y2r = apcr - bpdr, y2i = apci - bpdi;
        float y3r = amcr + bmdi, y3i = amci - bmdr;
        ur[4 * p + 0] = y0r;  ui[4 * p + 0] = y0i;
        cmul(y1r, y1i, WR[p][1], WI[p][1], ur[4 * p + 1], ui[4 * p + 1]);
        cmul(y2r, y2i, WR[p][2], WI[p][2], ur[4 * p + 2], ui[4 * p + 2]);
        cmul(y3r, y3i, WR[p][3], WI[p][3], ur[4 * p + 3], ui[4 * p + 3]);
    }
#pragma unroll
    for (int q = 0; q < 4; ++q) {
        float apcr = ur[q] + ur[q + 8],      apci = ui[q] + ui[q + 8];
        float amcr = ur[q] - ur[q + 8],      amci = ui[q] - ui[q + 8];
        float bpdr = ur[q + 4] + ur[q + 12], bpdi = ui[q + 4] + ui[q + 12];
        float bmdr = ur[q + 4] - ur[q + 12], bmdi = ui[q + 4] - ui[q + 12];
        vr[q]      = apcr + bpdr;  vi[q]      = apci + bpdi;
        vr[q + 4]  = amcr - bmdi;  vi[q + 4]  = amci + bmdr;
        vr[q + 8]  = apcr - bpdr;  vi[q + 8]  = apci - bpdi;
        vr[q + 12] = amcr + bmdi;  vi[q + 12] = amci - bmdr;
    }
}

// v[r] *= w1^r, r=1..15 (sequential power chain)
__device__ __forceinline__ void twiddle_apply(float vr[16], float vi[16],
                                              float w1r, float w1i) {
    float cr = w1r, ci = w1i;
#pragma unroll
    for (int r = 1; r < 16; ++r) {
        float tr, ti;
        cmul(vr[r], vi[r], cr, ci, tr, ti);
        vr[r] = tr; vi[r] = ti;
        if (r < 15) {
            float nr, ni;
            cmul(cr, ci, w1r, w1i, nr, ni);
            cr = nr; ci = ni;
        }
    }
}

extern "C" __global__ void __launch_bounds__(NT, 5)
idct_fft_kernel(const float* __restrict__ x, const float* __restrict__ expk,
                float* __restrict__ out)
{
    __shared__ __align__(16) float2 S[NFFT];      // exactly 32 KB
    float* __restrict__ Sf = (float*)S;

    const int tid = threadIdx.x;
    const long row = blockIdx.x;
    const float* __restrict__ xrow = x + row * (long)NFFT;
    const float2* __restrict__ e2 = (const float2*)expk;

    // ---- stage 1 (s = 1): fused global load + premultiply ----
    float vr[16], vi[16];
#pragma unroll
    for (int j = 0; j < 16; ++j) {
        int n = tid + NT * j;
        float xv = xrow[n];
        float2 e = e2[n];                       // (cos t, -sin t), t = pi*n/(2N)
        float w = (n == 0) ? 1.0f : 2.0f;
        vr[j] = w * xv * e.x;
        vi[j] = -(w * xv * e.y);
    }
    dft16(vr, vi);
    {
        float2 we = e2[4 * tid];                // exp(+i*2pi*tid/N) = (we.x, -we.y)
        twiddle_apply(vr, vi, we.x, -we.y);
    }
    // b128 stores: pair (r, r+1) stays adjacent under SWZ (mask has bit0=0)
#pragma unroll
    for (int rp = 0; rp < 8; ++rp) {
        int p = 16 * tid + 2 * rp;
        float4 st = make_float4(vr[2 * rp], vi[2 * rp], vr[2 * rp + 1], vi[2 * rp + 1]);
        *(float4*)&S[SWZ(p)] = st;
    }
    __syncthreads();

    // ---- stage 2 (s = 16) ----
#pragma unroll
    for (int j = 0; j < 16; ++j) {
        float2 c = S[SWZ(tid + NT * j)];
        vr[j] = c.x; vi[j] = c.y;
    }
    __syncthreads();                            // all reads done before in-place writes
    dft16(vr, vi);
    {
        float2 we = e2[64 * (tid >> 4)];        // exp(+i*2pi*16*(tid>>4)/N)
        twiddle_apply(vr, vi, we.x, -we.y);
    }
    {
        int ba = (tid & 15) + ((tid >> 4) << 8);   // q + 256*p'
#pragma unroll
        for (int r = 0; r < 16; ++r) {
            S[SWZ(ba + 16 * r)] = make_float2(vr[r], vi[r]);
        }
    }
    __syncthreads();

    // ---- stage 3 (s = 256): twiddles unity; only real part needed ----
#pragma unroll
    for (int j = 0; j < 16; ++j) {
        float2 c = S[SWZ(tid + NT * j)];
        vr[j] = c.x; vi[j] = c.y;
    }
    __syncthreads();
    dft16(vr, vi);
#pragma unroll
    for (int r = 0; r < 16; ++r) {
        Sf[tid + NT * r] = vr[r];               // linear float layout, lane-consecutive
    }
    __syncthreads();

    // ---- output: y[2m] = Re u[m], y[2m+1] = Re u[N-1-m] ----
    float2* __restrict__ y2 = (float2*)(out + row * (long)NFFT);
#pragma unroll
    for (int t = 0; t < 8; ++t) {
        int m = tid + NT * t;
        float a = Sf[m];
        float b = Sf[NFFT - 1 - m];
        y2[m] = make_float2(a, b);              // coalesced 8B/lane stores
    }
}

extern "C" void kernel_launch(void* const* d_in, const int* in_sizes, int n_in,
                              void* d_out, int out_size, void* d_ws, size_t ws_size,
                              hipStream_t stream) {
    const float* x    = (const float*)d_in[0];
    const float* expk = (const float*)d_in[1];
    float* out        = (float*)d_out;
    const int nrows   = in_sizes[0] / NFFT;     // 4096 rows
    hipLaunchKernelGGL(idct_fft_kernel, dim3(nrows), dim3(NT), 0, stream,
                       x, expk, out);
}

// Round 3
// 137.021 us; speedup vs baseline: 1.0540x; 1.0540x over previous
//
#include <hip/hip_runtime.h>

// IDCT (DCT-III), 4096 rows x N=4096, via per-row M=N/2=2048-point complex FFT
// (Hermitian fold of the Makhoul N-point formulation):
//   h_k = e^{i*pi*k/2N} (x_k - i x_{N-k}),  x_N := 0          (Hermitian)
//   Z_k = (h_k + h_{k+M}) + i w_k (h_k - h_{k+M}),  w_k = e^{2pi i k/N}, k<M
//   z   = IDFT_M(Z)  (unnormalized, sign +1)
//   H_{2m} = Re z_m, H_{2m+1} = Im z_m   (H = Re of N-point IDFT of a)
//   y[2m] = H_m, y[2m+1] = H_{N-1-m}
// => y[4u] = Re z_u, y[4u+1] = Im z_{M-1-u}, y[4u+2] = Im z_u, y[4u+3] = Re z_{M-1-u}
//
// 128 threads/block, one block per row. M = 16*8*16, 3 stages, 16 complex/thread.
// LDS = 2048 float2 = 16 KB, XOR-swizzled (a ^ (((a>>4)&7)<<1)), <=2-way everywhere.
// R3 vs R2 (61us): R2 spilled (VGPR cap 48, WRITE_SIZE 112MB). Halved FFT removes
// both the work and the pressure; launch_bounds(128,2) = 256-VGPR budget, no spill.

#define NROW 4096
#define M    2048
#define NT   128
#define SWZ2(a) ((a) ^ ((((a) >> 4) & 7) << 1))

__device__ __forceinline__ void cmul(float ar, float ai, float br, float bi,
                                     float& orr, float& oii) {
    orr = ar * br - ai * bi;
    oii = ar * bi + ai * br;
}

// 16-point DFT, sign +1, natural order, in place (verified in R1/R2).
__device__ __forceinline__ void dft16(float vr[16], float vi[16]) {
    constexpr float WR[4][4] = {
        {1.f, 1.f, 1.f, 1.f},
        {1.f,  0.92387953251128674f,  0.70710678118654752f,  0.38268343236508977f},
        {1.f,  0.70710678118654752f,  0.f,                  -0.70710678118654752f},
        {1.f,  0.38268343236508977f, -0.70710678118654752f, -0.92387953251128674f}};
    constexpr float WI[4][4] = {
        {0.f, 0.f, 0.f, 0.f},
        {0.f,  0.38268343236508977f,  0.70710678118654752f,  0.92387953251128674f},
        {0.f,  0.70710678118654752f,  1.f,                   0.70710678118654752f},
        {0.f,  0.92387953251128674f,  0.70710678118654752f, -0.38268343236508977f}};
    float ur[16], ui[16];
#pragma unroll
    for (int p = 0; p < 4; ++p) {
        float apcr = vr[p] + vr[p + 8],      apci = vi[p] + vi[p + 8];
        float amcr = vr[p] - vr[p + 8],      amci = vi[p] - vi[p + 8];
        float bpdr = vr[p + 4] + vr[p + 12], bpdi = vi[p + 4] + vi[p + 12];
        float bmdr = vr[p + 4] - vr[p + 12], bmdi = vi[p + 4] - vi[p + 12];
        float y0r = apcr + bpdr, y0i = apci + bpdi;
        float y1r = amcr - bmdi, y1i = amci + bmdr;
        float y2r = apcr - bpdr, y2i = apci - bpdi;
        float y3r = amcr + bmdi, y3i = amci - bmdr;
        ur[4 * p + 0] = y0r;  ui[4 * p + 0] = y0i;
        cmul(y1r, y1i, WR[p][1], WI[p][1], ur[4 * p + 1], ui[4 * p + 1]);
        cmul(y2r, y2i, WR[p][2], WI[p][2], ur[4 * p + 2], ui[4 * p + 2]);
        cmul(y3r, y3i, WR[p][3], WI[p][3], ur[4 * p + 3], ui[4 * p + 3]);
    }
#pragma unroll
    for (int q = 0; q < 4; ++q) {
        float apcr = ur[q] + ur[q + 8],      apci = ui[q] + ui[q + 8];
        float amcr = ur[q] - ur[q + 8],      amci = ui[q] - ui[q + 8];
        float bpdr = ur[q + 4] + ur[q + 12], bpdi = ui[q + 4] + ui[q + 12];
        float bmdr = ur[q + 4] - ur[q + 12], bmdi = ui[q + 4] - ui[q + 12];
        vr[q]      = apcr + bpdr;  vi[q]      = apci + bpdi;
        vr[q + 4]  = amcr - bmdi;  vi[q + 4]  = amci + bmdr;
        vr[q + 8]  = apcr - bpdr;  vi[q + 8]  = apci - bpdi;
        vr[q + 12] = amcr + bmdi;  vi[q + 12] = amci - bmdr;
    }
}

__device__ __forceinline__ void dft4(float& ar, float& ai, float& br, float& bi,
                                     float& cr, float& ci, float& dr, float& di) {
    // sign +1: X = [a+b+c+d, (a-c)+i(b-d), a-b+c-d, (a-c)-i(b-d)]
    float s02r = ar + cr, s02i = ai + ci;
    float d02r = ar - cr, d02i = ai - ci;
    float s13r = br + dr, s13i = bi + di;
    float d13r = br - dr, d13i = bi - di;
    ar = s02r + s13r; ai = s02i + s13i;
    br = d02r - d13i; bi = d02i + d13r;
    cr = s02r - s13r; ci = s02i - s13i;
    dr = d02r + d13i; di = d02i - d13r;
}

// 8-point DFT, sign +1, natural order, in place on vr[0..7]/vi[0..7].
__device__ __forceinline__ void dft8(float* vr, float* vi) {
    float er[4]  = {vr[0], vr[2], vr[4], vr[6]};
    float ei[4]  = {vi[0], vi[2], vi[4], vi[6]};
    float odr[4] = {vr[1], vr[3], vr[5], vr[7]};
    float odi[4] = {vi[1], vi[3], vi[5], vi[7]};
    dft4(er[0], ei[0], er[1], ei[1], er[2], ei[2], er[3], ei[3]);
    dft4(odr[0], odi[0], odr[1], odi[1], odr[2], odi[2], odr[3], odi[3]);
    const float s = 0.70710678118654752f;
    vr[0] = er[0] + odr[0];            vi[0] = ei[0] + odi[0];
    vr[4] = er[0] - odr[0];            vi[4] = ei[0] - odi[0];
    float t1r = s * (odr[1] - odi[1]), t1i = s * (odr[1] + odi[1]);  // w8^1 * O1
    vr[1] = er[1] + t1r;               vi[1] = ei[1] + t1i;
    vr[5] = er[1] - t1r;               vi[5] = ei[1] - t1i;
    vr[2] = er[2] - odi[2];            vi[2] = ei[2] + odr[2];       // w8^2 = i
    vr[6] = er[2] + odi[2];            vi[6] = ei[2] - odr[2];
    float t3r = -s * (odr[3] + odi[3]), t3i = s * (odr[3] - odi[3]); // w8^3
    vr[3] = er[3] + t3r;               vi[3] = ei[3] + t3i;
    vr[7] = er[3] - t3r;               vi[7] = ei[3] - t3i;
}

// v[r] *= w1^r for r=1..15
__device__ __forceinline__ void twiddle_apply(float vr[16], float vi[16],
                                              float w1r, float w1i) {
    float cr = w1r, ci = w1i;
#pragma unroll
    for (int r = 1; r < 16; ++r) {
        float tr, ti;
        cmul(vr[r], vi[r], cr, ci, tr, ti);
        vr[r] = tr; vi[r] = ti;
        if (r < 15) { float nr, ni; cmul(cr, ci, w1r, w1i, nr, ni); cr = nr; ci = ni; }
    }
}

// v[r] *= w1^r for r=1..7
__device__ __forceinline__ void twiddle_apply8(float* vr, float* vi,
                                               float w1r, float w1i) {
    float cr = w1r, ci = w1i;
#pragma unroll
    for (int r = 1; r < 8; ++r) {
        float tr, ti;
        cmul(vr[r], vi[r], cr, ci, tr, ti);
        vr[r] = tr; vi[r] = ti;
        if (r < 7) { float nr, ni; cmul(cr, ci, w1r, w1i, nr, ni); cr = nr; ci = ni; }
    }
}

extern "C" __global__ void __launch_bounds__(NT, 2)
idct_fft_kernel(const float* __restrict__ x, const float* __restrict__ expk,
                float* __restrict__ out)
{
    __shared__ __align__(16) float2 S[M];            // 16 KB
    const int tid = threadIdx.x;
    const long row = blockIdx.x;
    const float* __restrict__ xp = x + row * (long)NROW;
    const float2* __restrict__ e2 = (const float2*)expk;

    float vr[16], vi[16];

    // ---- build Z_k and stage 1: radix-16 over j (k = tid + 128 j) ----
#pragma unroll
    for (int j = 0; j < 16; ++j) {
        int k = tid + NT * j;                        // [0, M)
        float x1  = xp[k];
        float x2  = xp[k + M];
        float xr1 = (k == 0) ? 0.0f : xp[NROW - k];
        float xr2 = xp[M - k];
        float2 E1 = e2[k];
        float2 E2 = e2[k + M];
        float c1 = E1.x, s1 = -E1.y;
        float c2 = E2.x, s2 = -E2.y;
        float h1r = c1 * x1 + s1 * xr1, h1i = s1 * x1 - c1 * xr1;
        float h2r = c2 * x2 + s2 * xr2, h2i = s2 * x2 - c2 * xr2;
        int hi = (k >= 1024);
        float2 EW = e2[(4 * k) & (NROW - 1)];
        float wr = hi ? EW.y : EW.x;                 // w_k = e^{2pi i k/N}
        float wi = hi ? EW.x : -EW.y;
        float Sr = h1r + h2r, Si = h1i + h2i;
        float Dr = h1r - h2r, Di = h1i - h2i;
        vr[j] = Sr - (wr * Di + wi * Dr);            // Z = S + i*w*D
        vi[j] = Si + (wr * Dr - wi * Di);
    }
    dft16(vr, vi);
    { float2 E = e2[8 * tid]; twiddle_apply(vr, vi, E.x, -E.y); }   // W_M^{tid*p}
#pragma unroll
    for (int rp = 0; rp < 8; ++rp) {
        int a = 16 * tid + 2 * rp;
        *(float4*)&S[SWZ2(a)] =
            make_float4(vr[2 * rp], vi[2 * rp], vr[2 * rp + 1], vi[2 * rp + 1]);
    }
    __syncthreads();

    // ---- stage 2: two radix-8 over t1 (t = t0 + 16 t1) ----
    const int p2 = tid & 15, t0a = tid >> 4;         // t0a in [0,8)
#pragma unroll
    for (int h = 0; h < 2; ++h) {
        int t0 = t0a + 8 * h;
#pragma unroll
        for (int t1 = 0; t1 < 8; ++t1) {
            float2 c = S[SWZ2(16 * t0 + 256 * t1 + p2)];
            vr[8 * h + t1] = c.x; vi[8 * h + t1] = c.y;
        }
    }
    __syncthreads();                                 // reads done before in-place writes
    dft8(vr, vi);
    dft8(vr + 8, vi + 8);
    { float2 E = e2[128 * t0a];       twiddle_apply8(vr, vi, E.x, -E.y); }      // e^{2pi i t0 q0/128}
    { float2 E = e2[128 * (t0a + 8)]; twiddle_apply8(vr + 8, vi + 8, E.x, -E.y); }
#pragma unroll
    for (int h = 0; h < 2; ++h) {
        int t0 = t0a + 8 * h;
#pragma unroll
        for (int q0 = 0; q0 < 8; ++q0) {
            S[SWZ2(t0 + 16 * p2 + 256 * q0)] = make_float2(vr[8 * h + q0], vi[8 * h + q0]);
        }
    }
    __syncthreads();

    // ---- stage 3: radix-16 over t0 ----
    const int p3 = tid & 15, q03 = tid >> 4;         // q03 in [0,8)
    {
        int base = 16 * p3 + 256 * q03;
#pragma unroll
        for (int tp = 0; tp < 8; ++tp) {
            float4 c = *(const float4*)&S[SWZ2(base + 2 * tp)];
            vr[2 * tp] = c.x; vi[2 * tp] = c.y; vr[2 * tp + 1] = c.z; vi[2 * tp + 1] = c.w;
        }
    }
    __syncthreads();
    dft16(vr, vi);                                   // no twiddle (last stage)
#pragma unroll
    for (int q1 = 0; q1 < 16; ++q1) {
        S[SWZ2(tid + 128 * q1)] = make_float2(vr[q1], vi[q1]);   // z at natural addr
    }
    __syncthreads();

    // ---- unpack: y[4u]=Re z_u, y[4u+1]=Im z_{M-1-u}, y[4u+2]=Im z_u, y[4u+3]=Re z_{M-1-u}
    float4* __restrict__ y4 = (float4*)(out + row * (long)NROW);
#pragma unroll
    for (int v = 0; v < 8; ++v) {
        int u = tid + NT * v;                        // [0, 1024)
        float2 zu = S[SWZ2(u)];
        float2 zv = S[SWZ2(M - 1 - u)];
        y4[u] = make_float4(zu.x, zv.y, zu.y, zv.x);
    }
}

extern "C" void kernel_launch(void* const* d_in, const int* in_sizes, int n_in,
                              void* d_out, int out_size, void* d_ws, size_t ws_size,
                              hipStream_t stream) {
    const float* x    = (const float*)d_in[0];
    const float* expk = (const float*)d_in[1];
    float* out        = (float*)d_out;
    const int nrows   = in_sizes[0] / NROW;          // 4096 rows
    hipLaunchKernelGGL(idct_fft_kernel, dim3(nrows), dim3(NT), 0, stream,
                       x, expk, out);
}

// Round 4
// 133.562 us; speedup vs baseline: 1.0813x; 1.0259x over previous
//
#include <hip/hip_runtime.h>

// IDCT (DCT-III), 4096 rows x N=4096, via per-row M=2048-point complex FFT
// (Hermitian fold of Makhoul, verified R3):
//   h_k = e^{i pi k/2N}(x_k - i x_{N-k});  Z_k = (h_k+h_{k+M}) + i w_k (h_k-h_{k+M})
//   z = IDFT_M(Z);  y[4u]=Re z_u, y[4u+1]=Im z_{M-1-u}, y[4u+2]=Im z_u, y[4u+3]=Re z_{M-1-u}
//
// R4 structure: 256 threads/row, 8 complex/thread, radices [8,8,8,4], Stockham
// (twiddle inputs by w_{sR}^{p r}; write p + s(q + R t); verified on M=4,8 traces).
// Ping-pong LDS 2x16KB -> 3 barriers; stage-4 handles p=tid AND p=511-tid so the
// (u, 2047-u) output pairs are thread-local -> unpack straight from registers.
// Swizzle a ^ (((a>>6)&7)<<1): all LDS patterns at conflict-free minimum.

#define NROW 4096
#define MM   2048
#define NT   256
#define SWZ(a) ((a) ^ ((((a) >> 6) & 7) << 1))

__device__ __forceinline__ void cmul(float ar, float ai, float br, float bi,
                                     float& orr, float& oii) {
    orr = ar * br - ai * bi;
    oii = ar * bi + ai * br;
}

__device__ __forceinline__ void dft4(float& ar, float& ai, float& br, float& bi,
                                     float& cr, float& ci, float& dr, float& di) {
    // sign +1: X = [a+b+c+d, (a-c)+i(b-d), a-b+c-d, (a-c)-i(b-d)]
    float s02r = ar + cr, s02i = ai + ci;
    float d02r = ar - cr, d02i = ai - ci;
    float s13r = br + dr, s13i = bi + di;
    float d13r = br - dr, d13i = bi - di;
    ar = s02r + s13r; ai = s02i + s13i;
    br = d02r - d13i; bi = d02i + d13r;
    cr = s02r - s13r; ci = s02i - s13i;
    dr = d02r + d13i; di = d02i - d13r;
}

// 8-point DFT, sign +1, natural order, in place (verified R3).
__device__ __forceinline__ void dft8(float* vr, float* vi) {
    float er[4]  = {vr[0], vr[2], vr[4], vr[6]};
    float ei[4]  = {vi[0], vi[2], vi[4], vi[6]};
    float odr[4] = {vr[1], vr[3], vr[5], vr[7]};
    float odi[4] = {vi[1], vi[3], vi[5], vi[7]};
    dft4(er[0], ei[0], er[1], ei[1], er[2], ei[2], er[3], ei[3]);
    dft4(odr[0], odi[0], odr[1], odi[1], odr[2], odi[2], odr[3], odi[3]);
    const float s = 0.70710678118654752f;
    vr[0] = er[0] + odr[0];            vi[0] = ei[0] + odi[0];
    vr[4] = er[0] - odr[0];            vi[4] = ei[0] - odi[0];
    float t1r = s * (odr[1] - odi[1]), t1i = s * (odr[1] + odi[1]);
    vr[1] = er[1] + t1r;               vi[1] = ei[1] + t1i;
    vr[5] = er[1] - t1r;               vi[5] = ei[1] - t1i;
    vr[2] = er[2] - odi[2];            vi[2] = ei[2] + odr[2];
    vr[6] = er[2] + odi[2];            vi[6] = ei[2] - odr[2];
    float t3r = -s * (odr[3] + odi[3]), t3i = s * (odr[3] - odi[3]);
    vr[3] = er[3] + t3r;               vi[3] = ei[3] + t3i;
    vr[7] = er[3] - t3r;               vi[7] = ei[3] - t3i;
}

// inputs v[r] *= w1^r, r=1..7 (chain; exponents stay < root order, no wrap)
__device__ __forceinline__ void twiddle_in8(float* vr, float* vi,
                                            float w1r, float w1i) {
    float cr = w1r, ci = w1i;
#pragma unroll
    for (int r = 1; r < 8; ++r) {
        float tr, ti;
        cmul(vr[r], vi[r], cr, ci, tr, ti);
        vr[r] = tr; vi[r] = ti;
        if (r < 7) { float nr, ni; cmul(cr, ci, w1r, w1i, nr, ni); cr = nr; ci = ni; }
    }
}

extern "C" __global__ void __launch_bounds__(NT, 6)
idct_fft_kernel(const float* __restrict__ x, const float* __restrict__ expk,
                float* __restrict__ out)
{
    __shared__ __align__(16) float2 BA[MM];     // 16 KB
    __shared__ __align__(16) float2 BB[MM];     // 16 KB
    const int tid = threadIdx.x;
    const long row = blockIdx.x;
    const float* __restrict__ xp = x + row * (long)NROW;
    const float2* __restrict__ e2 = (const float2*)expk;

    float vr[8], vi[8];

    // ---- build Z_k (k = tid + 256 r) + stage 1: radix-8, s=1, no twiddle ----
#pragma unroll
    for (int r = 0; r < 8; ++r) {
        int k = tid + NT * r;                    // [0, 2048)
        float x1  = xp[k];
        float x2  = xp[k + MM];
        float xr1 = (k == 0) ? 0.0f : xp[NROW - k];
        float xr2 = xp[MM - k];
        float2 E1 = e2[k];
        float2 E2 = e2[k + MM];
        float c1 = E1.x, s1 = -E1.y;
        float c2 = E2.x, s2 = -E2.y;
        float h1r = c1 * x1 + s1 * xr1, h1i = s1 * x1 - c1 * xr1;
        float h2r = c2 * x2 + s2 * xr2, h2i = s2 * x2 - c2 * xr2;
        int hi = (k >= 1024);
        float2 EW = e2[(4 * k) & (NROW - 1)];
        float wr = hi ? EW.y : EW.x;             // w_k = e^{2pi i k/N}
        float wi = hi ? EW.x : -EW.y;
        float Sr = h1r + h2r, Si = h1i + h2i;
        float Dr = h1r - h2r, Di = h1i - h2i;
        vr[r] = Sr - (wr * Di + wi * Dr);        // Z = S + i*w*D
        vi[r] = Si + (wr * Dr - wi * Di);
    }
    dft8(vr, vi);
#pragma unroll
    for (int j = 0; j < 4; ++j) {
        int a = 8 * tid + 2 * j;                 // write p + s(q + R t) = q + 8 tid
        *(float4*)&BA[SWZ(a)] =
            make_float4(vr[2 * j], vi[2 * j], vr[2 * j + 1], vi[2 * j + 1]);
    }
    __syncthreads();

    // ---- stage 2: s=8, R=8; p = tid&7, t = tid>>3 ----
#pragma unroll
    for (int r = 0; r < 8; ++r) {
        float2 c = BA[SWZ(tid + 256 * r)];       // p + 8(t + 32 r)
        vr[r] = c.x; vi[r] = c.y;
    }
    {
        float2 E = e2[256 * (tid & 7)];          // w1 = omega_64^p
        twiddle_in8(vr, vi, E.x, -E.y);
    }
    dft8(vr, vi);
    {
        int p = tid & 7, t = tid >> 3;
#pragma unroll
        for (int q = 0; q < 8; ++q)
            BB[SWZ(p + 8 * q + 64 * t)] = make_float2(vr[q], vi[q]);
    }
    __syncthreads();

    // ---- stage 3: s=64, R=8; p = tid&63, t = tid>>6 ----
#pragma unroll
    for (int r = 0; r < 8; ++r) {
        float2 c = BB[SWZ(tid + 256 * r)];       // p + 64(t + 4 r)
        vr[r] = c.x; vi[r] = c.y;
    }
    {
        float2 E = e2[32 * (tid & 63)];          // w1 = omega_512^p
        twiddle_in8(vr, vi, E.x, -E.y);
    }
    dft8(vr, vi);
    {
        int p = tid & 63, t = tid >> 6;
#pragma unroll
        for (int q = 0; q < 8; ++q)
            BA[SWZ(p + 64 * q + 512 * t)] = make_float2(vr[q], vi[q]);
    }
    __syncthreads();

    // ---- stage 4: s=512, R=4; butterflies p = tid and p = 511-tid ----
    float ar[4], ai[4], br4[4], bi4[4];
    const int pB = 511 - tid;
#pragma unroll
    for (int r = 0; r < 4; ++r) {
        float2 cA = BA[SWZ(tid + 512 * r)];
        ar[r] = cA.x; ai[r] = cA.y;
        float2 cB = BA[SWZ(pB + 512 * r)];
        br4[r] = cB.x; bi4[r] = cB.y;
    }
    {   // twiddle inputs by omega_2048^{p r}: w1 = e2[8p] (8p <= 4088, in range)
        float2 EA = e2[8 * tid];
        float wAr = EA.x, wAi = -EA.y, cr = wAr, ci = wAi;
#pragma unroll
        for (int r = 1; r < 4; ++r) {
            float tr, ti; cmul(ar[r], ai[r], cr, ci, tr, ti); ar[r] = tr; ai[r] = ti;
            if (r < 3) { float nr, ni; cmul(cr, ci, wAr, wAi, nr, ni); cr = nr; ci = ni; }
        }
        float2 EB = e2[8 * pB];
        float wBr = EB.x, wBi = -EB.y; cr = wBr; ci = wBi;
#pragma unroll
        for (int r = 1; r < 4; ++r) {
            float tr, ti; cmul(br4[r], bi4[r], cr, ci, tr, ti); br4[r] = tr; bi4[r] = ti;
            if (r < 3) { float nr, ni; cmul(cr, ci, wBr, wBi, nr, ni); cr = nr; ci = ni; }
        }
    }
    dft4(ar[0], ai[0], ar[1], ai[1], ar[2], ai[2], ar[3], ai[3]);
    dft4(br4[0], bi4[0], br4[1], bi4[1], br4[2], bi4[2], br4[3], bi4[3]);
    // zA_q = z[tid + 512 q], zB_q = z[511 - tid + 512 q]

    // ---- unpack (thread-local pairs), 4 coalesced float4 stores ----
    float4* __restrict__ y4 = (float4*)(out + row * (long)NROW);
    y4[tid]        = make_float4(ar[0],  bi4[3], ai[0],  br4[3]);  // u = tid
    y4[tid + 512]  = make_float4(ar[1],  bi4[2], ai[1],  br4[2]);  // u = tid+512
    y4[1023 - tid] = make_float4(br4[1], ai[2],  bi4[1], ar[2]);   // u = 1023-tid
    y4[511 - tid]  = make_float4(br4[0], ai[3],  bi4[0], ar[3]);   // u = 511-tid
}

extern "C" void kernel_launch(void* const* d_in, const int* in_sizes, int n_in,
                              void* d_out, int out_size, void* d_ws, size_t ws_size,
                              hipStream_t stream) {
    const float* x    = (const float*)d_in[0];
    const float* expk = (const float*)d_in[1];
    float* out        = (float*)d_out;
    const int nrows   = in_sizes[0] / NROW;      // 4096 rows
    hipLaunchKernelGGL(idct_fft_kernel, dim3(nrows), dim3(NT), 0, stream,
                       x, expk, out);
}

// Round 5
// 124.927 us; speedup vs baseline: 1.1560x; 1.0691x over previous
//
#include <hip/hip_runtime.h>

// IDCT (DCT-III), 4096 rows x N=4096, via per-row M=2048-point complex FFT
// (Hermitian fold of Makhoul, math verified R3/R4):
//   h_k = e^{i pi k/2N}(x_k - i x_{N-k});  Z_k = (h_k+h_{k+M}) + i w_k (h_k-h_{k+M})
//   z = IDFT_M(Z);  y[4u]=Re z_u, y[4u+1]=Im z_{M-1-u}, y[4u+2]=Im z_u, y[4u+3]=Re z_{M-1-u}
//
// R5 vs R4 (50us; tail-bound at 5 blocks/CU, 2.1M LDS conflicts from the f4
// stage-3 read):
//  - single in-place 16KB LDS buffer, read/barrier/write per stage ->
//    8 blocks/CU (32-wave cap = 100% occupancy cap), 16 blocks/CU = 2 exact
//    rounds of 8, no residency tail
//  - E2 = e^{i(theta+pi/4)} and w_k = e^{i*4theta} computed from E1 by rotation /
//    double-angle (removes 16 loads/thread incl. the stride-4 gather)
//  - all strided LDS ops are the clean a = tid + 256r b64 form; conflicted
//    f4-read pattern removed
//  - launch_bounds(256,8): 64-VGPR budget (R4 compiled this math to 48)

#define NROW 4096
#define MM   2048
#define NT   256
#define SWZ(a) ((a) ^ ((((a) >> 6) & 7) << 1))

__device__ __forceinline__ void cmul(float ar, float ai, float br, float bi,
                                     float& orr, float& oii) {
    orr = ar * br - ai * bi;
    oii = ar * bi + ai * br;
}

__device__ __forceinline__ void dft4(float& ar, float& ai, float& br, float& bi,
                                     float& cr, float& ci, float& dr, float& di) {
    // sign +1: X = [a+b+c+d, (a-c)+i(b-d), a-b+c-d, (a-c)-i(b-d)]
    float s02r = ar + cr, s02i = ai + ci;
    float d02r = ar - cr, d02i = ai - ci;
    float s13r = br + dr, s13i = bi + di;
    float d13r = br - dr, d13i = bi - di;
    ar = s02r + s13r; ai = s02i + s13i;
    br = d02r - d13i; bi = d02i + d13r;
    cr = s02r - s13r; ci = s02i - s13i;
    dr = d02r + d13i; di = d02i - d13r;
}

// 8-point DFT, sign +1, natural order, in place (verified R3/R4).
__device__ __forceinline__ void dft8(float* vr, float* vi) {
    float er[4]  = {vr[0], vr[2], vr[4], vr[6]};
    float ei[4]  = {vi[0], vi[2], vi[4], vi[6]};
    float odr[4] = {vr[1], vr[3], vr[5], vr[7]};
    float odi[4] = {vi[1], vi[3], vi[5], vi[7]};
    dft4(er[0], ei[0], er[1], ei[1], er[2], ei[2], er[3], ei[3]);
    dft4(odr[0], odi[0], odr[1], odi[1], odr[2], odi[2], odr[3], odi[3]);
    const float s = 0.70710678118654752f;
    vr[0] = er[0] + odr[0];            vi[0] = ei[0] + odi[0];
    vr[4] = er[0] - odr[0];            vi[4] = ei[0] - odi[0];
    float t1r = s * (odr[1] - odi[1]), t1i = s * (odr[1] + odi[1]);
    vr[1] = er[1] + t1r;               vi[1] = ei[1] + t1i;
    vr[5] = er[1] - t1r;               vi[5] = ei[1] - t1i;
    vr[2] = er[2] - odi[2];            vi[2] = ei[2] + odr[2];
    vr[6] = er[2] + odi[2];            vi[6] = ei[2] - odr[2];
    float t3r = -s * (odr[3] + odi[3]), t3i = s * (odr[3] - odi[3]);
    vr[3] = er[3] + t3r;               vi[3] = ei[3] + t3i;
    vr[7] = er[3] - t3r;               vi[7] = ei[3] - t3i;
}

// inputs v[r] *= w1^r, r=1..7
__device__ __forceinline__ void twiddle_in8(float* vr, float* vi,
                                            float w1r, float w1i) {
    float cr = w1r, ci = w1i;
#pragma unroll
    for (int r = 1; r < 8; ++r) {
        float tr, ti;
        cmul(vr[r], vi[r], cr, ci, tr, ti);
        vr[r] = tr; vi[r] = ti;
        if (r < 7) { float nr, ni; cmul(cr, ci, w1r, w1i, nr, ni); cr = nr; ci = ni; }
    }
}

extern "C" __global__ void __launch_bounds__(NT, 8)
idct_fft_kernel(const float* __restrict__ x, const float* __restrict__ expk,
                float* __restrict__ out)
{
    __shared__ __align__(16) float2 S[MM];       // 16 KB -> 8 blocks/CU (wave cap)
    const int tid = threadIdx.x;
    const long row = blockIdx.x;
    const float* __restrict__ xp = x + row * (long)NROW;
    const float2* __restrict__ e2 = (const float2*)expk;

    float vr[8], vi[8];

    // ---- build Z_k (k = tid + 256 r) + stage 1: radix-8, s=1, no twiddle ----
    const float R2H = 0.70710678118654752f;      // sqrt(2)/2
#pragma unroll
    for (int r = 0; r < 8; ++r) {
        int k = tid + NT * r;                    // [0, 2048)
        float x1  = xp[k];
        float x2  = xp[k + MM];
        float xr1 = (k == 0) ? 0.0f : xp[NROW - k];
        float xr2 = xp[MM - k];
        float2 E1 = e2[k];                       // (cos th, -sin th), th = pi k/8192
        float c1 = E1.x, s1 = -E1.y;
        // E2 = e^{i(th + pi/4)}: rotation by sqrt2/2
        float c2 = (c1 - s1) * R2H;
        float s2 = (c1 + s1) * R2H;
        // w_k = e^{i 4 th} via double-angle twice (th < pi/4, well-conditioned)
        float c2t = 2.0f * c1 * c1 - 1.0f;
        float s2t = 2.0f * s1 * c1;
        float wr  = 2.0f * c2t * c2t - 1.0f;
        float wi  = 2.0f * s2t * c2t;
        float h1r = c1 * x1 + s1 * xr1, h1i = s1 * x1 - c1 * xr1;
        float h2r = c2 * x2 + s2 * xr2, h2i = s2 * x2 - c2 * xr2;
        float Sr = h1r + h2r, Si = h1i + h2i;
        float Dr = h1r - h2r, Di = h1i - h2i;
        vr[r] = Sr - (wr * Di + wi * Dr);        // Z = S + i*w*D
        vi[r] = Si + (wr * Dr - wi * Di);
    }
    dft8(vr, vi);
#pragma unroll
    for (int j = 0; j < 4; ++j) {
        int a = 8 * tid + 2 * j;                 // z-index q + 8*tid
        *(float4*)&S[SWZ(a)] =
            make_float4(vr[2 * j], vi[2 * j], vr[2 * j + 1], vi[2 * j + 1]);
    }
    __syncthreads();

    // ---- stage 2: s=8, R=8; p = tid&7, t = tid>>3 ----
#pragma unroll
    for (int r = 0; r < 8; ++r) {
        float2 c = S[SWZ(tid + 256 * r)];        // p + 8(t + 32 r)
        vr[r] = c.x; vi[r] = c.y;
    }
    __syncthreads();                             // all reads before in-place writes
    {
        float2 E = e2[256 * (tid & 7)];          // w1 = omega_64^p
        twiddle_in8(vr, vi, E.x, -E.y);
    }
    dft8(vr, vi);
    {
        int p = tid & 7, t = tid >> 3;
#pragma unroll
        for (int q = 0; q < 8; ++q)
            S[SWZ(p + 8 * q + 64 * t)] = make_float2(vr[q], vi[q]);
    }
    __syncthreads();

    // ---- stage 3: s=64, R=8; p = tid&63, t = tid>>6 ----
#pragma unroll
    for (int r = 0; r < 8; ++r) {
        float2 c = S[SWZ(tid + 256 * r)];        // p + 64(t + 4 r)
        vr[r] = c.x; vi[r] = c.y;
    }
    __syncthreads();
    {
        float2 E = e2[32 * (tid & 63)];          // w1 = omega_512^p
        twiddle_in8(vr, vi, E.x, -E.y);
    }
    dft8(vr, vi);
    {
        int p = tid & 63, t = tid >> 6;
#pragma unroll
        for (int q = 0; q < 8; ++q)
            S[SWZ(p + 64 * q + 512 * t)] = make_float2(vr[q], vi[q]);
    }
    __syncthreads();

    // ---- stage 4: s=512, R=4; butterflies p = tid and p = 511-tid ----
    float ar[4], ai[4], br4[4], bi4[4];
    const int pB = 511 - tid;
#pragma unroll
    for (int r = 0; r < 4; ++r) {
        float2 cA = S[SWZ(tid + 512 * r)];
        ar[r] = cA.x; ai[r] = cA.y;
        float2 cB = S[SWZ(pB + 512 * r)];
        br4[r] = cB.x; bi4[r] = cB.y;
    }
    {   // twiddle inputs by omega_2048^{p r}: w1 = e2[8p]
        float2 EA = e2[8 * tid];
        float wAr = EA.x, wAi = -EA.y, cr = wAr, ci = wAi;
#pragma unroll
        for (int r = 1; r < 4; ++r) {
            float tr, ti; cmul(ar[r], ai[r], cr, ci, tr, ti); ar[r] = tr; ai[r] = ti;
            if (r < 3) { float nr, ni; cmul(cr, ci, wAr, wAi, nr, ni); cr = nr; ci = ni; }
        }
        float2 EB = e2[8 * pB];
        float wBr = EB.x, wBi = -EB.y; cr = wBr; ci = wBi;
#pragma unroll
        for (int r = 1; r < 4; ++r) {
            float tr, ti; cmul(br4[r], bi4[r], cr, ci, tr, ti); br4[r] = tr; bi4[r] = ti;
            if (r < 3) { float nr, ni; cmul(cr, ci, wBr, wBi, nr, ni); cr = nr; ci = ni; }
        }
    }
    dft4(ar[0], ai[0], ar[1], ai[1], ar[2], ai[2], ar[3], ai[3]);
    dft4(br4[0], bi4[0], br4[1], bi4[1], br4[2], bi4[2], br4[3], bi4[3]);
    // zA_q = z[tid + 512 q], zB_q = z[511 - tid + 512 q]

    // ---- unpack (thread-local pairs), 4 coalesced float4 stores ----
    float4* __restrict__ y4 = (float4*)(out + row * (long)NROW);
    y4[tid]        = make_float4(ar[0],  bi4[3], ai[0],  br4[3]);  // u = tid
    y4[tid + 512]  = make_float4(ar[1],  bi4[2], ai[1],  br4[2]);  // u = tid+512
    y4[1023 - tid] = make_float4(br4[1], ai[2],  bi4[1], ar[2]);   // u = 1023-tid
    y4[511 - tid]  = make_float4(br4[0], ai[3],  bi4[0], ar[3]);   // u = 511-tid
}

extern "C" void kernel_launch(void* const* d_in, const int* in_sizes, int n_in,
                              void* d_out, int out_size, void* d_ws, size_t ws_size,
                              hipStream_t stream) {
    const float* x    = (const float*)d_in[0];
    const float* expk = (const float*)d_in[1];
    float* out        = (float*)d_out;
    const int nrows   = in_sizes[0] / NROW;      // 4096 rows
    hipLaunchKernelGGL(idct_fft_kernel, dim3(nrows), dim3(NT), 0, stream,
                       x, expk, out);
}